// Round 1
// baseline (314.887 us; speedup 1.0000x reference)
//
#include <hip/hip_runtime.h>

#define BIGC 10000.0f

__global__ void __launch_bounds__(256) coupling_kernel(
    const float* __restrict__ x, const float* __restrict__ t_feat,
    const float* __restrict__ mask, const float* __restrict__ W1,
    const float* __restrict__ b1, const float* __restrict__ W2,
    const float* __restrict__ b2, float* __restrict__ out, int n)
{
    int i = blockIdx.x * blockDim.x + threadIdx.x;
    if (i >= n) return;

    // ---- load inputs ----
    const float x0 = x[3 * i + 0];
    const float x1 = x[3 * i + 1];
    const float x2 = x[3 * i + 2];

    float z[18];
    z[0] = tanhf(x0);
    z[1] = tanhf(x1);
    {
        const float4* tp = (const float4*)(t_feat + 16 * (long)i);
        float4 t0 = tp[0], t1 = tp[1], t2 = tp[2], t3 = tp[3];
        z[2]  = t0.x; z[3]  = t0.y; z[4]  = t0.z; z[5]  = t0.w;
        z[6]  = t1.x; z[7]  = t1.y; z[8]  = t1.z; z[9]  = t1.w;
        z[10] = t2.x; z[11] = t2.y; z[12] = t2.z; z[13] = t2.w;
        z[14] = t3.x; z[15] = t3.y; z[16] = t3.z; z[17] = t3.w;
    }

    // ---- layer 1: h = relu(z @ W1 + b1), W1 is (18,64) row-major ----
    // Weight indices are wave-uniform compile-time offsets -> s_load + v_fmac(v,s,v)
    float h[64];
#pragma unroll
    for (int j = 0; j < 64; ++j) h[j] = b1[j];
#pragma unroll
    for (int k = 0; k < 18; ++k) {
        const float zk = z[k];
#pragma unroll
        for (int j = 0; j < 64; ++j)
            h[j] = fmaf(zk, W1[k * 64 + j], h[j]);
    }

    // ---- layer 2: d = softplus(relu(h) @ W2 + b2) + 1e-4, W2 is (64,10) ----
    float d[10];
#pragma unroll
    for (int m = 0; m < 10; ++m) d[m] = b2[m];
#pragma unroll
    for (int j = 0; j < 64; ++j) {
        const float hj = fmaxf(h[j], 0.0f);
#pragma unroll
        for (int m = 0; m < 10; ++m)
            d[m] = fmaf(hj, W2[j * 10 + m], d[m]);
    }
#pragma unroll
    for (int m = 0; m < 10; ++m) {
        const float v = d[m];
        // jax.nn.softplus: max(v,0) + log1p(exp(-|v|))  (numerically stable)
        d[m] = fmaxf(v, 0.0f) + log1pf(expf(-fabsf(v))) + 0.0001f;
    }

    // ---- knots (_get_xy) ----
    const float dxl2 = d[0], dxl1 = d[1], dxr1 = d[2], dxr2 = d[3];
    const float dyl2 = d[4], dyl1 = d[5], dyr1 = d[6], dyr2 = d[7];
    const float kl = d[8] * 2.0f, kr = d[9] * 2.0f;

    const float xL1 = -dxl1,        yL1 = -dyl1;
    const float xL2 = -dxl1 - dxl2, yL2 = -dyl1 - dyl2;
    const float xR1 = dxr1,         yR1 = dyr1;
    const float xR2 = dxr1 + dxr2,  yR2 = dyr1 + dyr2;
    const float xR3 = xR2 + BIGC,   yR3 = fmaf(kr, BIGC, yR2);
    const float xL3 = xL2 - BIGC,   yL3 = fmaf(-kl, BIGC, yL2);

    const float kx[6] = { xL3, xL2, xL1, xR1, xR2, xR3 };
    const float ky[6] = { yL3, yL2, yL1, yR1, yR2, yR3 };

    // ---- interp ----
    float q = x2;
    q = fminf(fmaxf(q, xL3 * 0.99f), xR3 * 0.99f);

    float res = 0.0f;
#pragma unroll
    for (int s = 0; s < 5; ++s) {
        const bool in_range = (q >= kx[s]) && (q < kx[s + 1]);
        const float slope = (ky[s + 1] - ky[s]) / (kx[s + 1] - kx[s]);
        const float v = fmaf(slope, q - kx[s], ky[s]);
        res += in_range ? v : 0.0f;
    }

    // ---- output: [x0*mask0, x1*mask1, res] ----
    const float m0 = mask[0];
    const float m1 = mask[1];
    out[3 * i + 0] = x0 * m0;
    out[3 * i + 1] = x1 * m1;
    out[3 * i + 2] = res;
}

extern "C" void kernel_launch(void* const* d_in, const int* in_sizes, int n_in,
                              void* d_out, int out_size, void* d_ws, size_t ws_size,
                              hipStream_t stream) {
    const float* x      = (const float*)d_in[0];
    const float* t_feat = (const float*)d_in[1];
    const float* mask   = (const float*)d_in[2];
    const float* W1     = (const float*)d_in[3];
    const float* b1     = (const float*)d_in[4];
    const float* W2     = (const float*)d_in[5];
    const float* b2     = (const float*)d_in[6];
    float* out = (float*)d_out;

    const int n = in_sizes[0] / 3;  // N points
    const int block = 256;
    const int grid = (n + block - 1) / block;
    coupling_kernel<<<grid, block, 0, stream>>>(x, t_feat, mask, W1, b1, W2, b2, out, n);
}

// Round 2
// 288.369 us; speedup vs baseline: 1.0920x; 1.0920x over previous
//
#include <hip/hip_runtime.h>

#define BIGC 10000.0f

// Raw-HW transcendentals: v_exp_f32 / v_log_f32 are base-2, v_rcp_f32 ~1ulp.
__device__ __forceinline__ float fast_exp2(float x)  { return __builtin_amdgcn_exp2f(x); }
__device__ __forceinline__ float fast_log2(float x)  { return __builtin_amdgcn_logf(x); }
__device__ __forceinline__ float fast_rcp(float x)   { return __builtin_amdgcn_rcpf(x); }

// tanh(x) = sign(x) * (1 - 2/(exp2(2*log2(e)*|x|) + 1))
__device__ __forceinline__ float fast_tanh(float x) {
    const float ax = fabsf(x);
    const float e  = fast_exp2(ax * 2.8853900817779268f);  // e^(2|x|)
    const float r  = 1.0f - 2.0f * fast_rcp(e + 1.0f);
    return copysignf(r, x);
}

// softplus(v) = max(v,0) + ln(1 + exp(-|v|))
__device__ __forceinline__ float fast_softplus(float v) {
    const float e = fast_exp2(fabsf(v) * -1.4426950408889634f);  // exp(-|v|)
    const float l = fast_log2(1.0f + e) * 0.6931471805599453f;   // ln(1+e)
    return fmaxf(v, 0.0f) + l;
}

__global__ void __launch_bounds__(256) coupling_kernel(
    const float* __restrict__ x, const float* __restrict__ t_feat,
    const float* __restrict__ mask, const float* __restrict__ W1,
    const float* __restrict__ b1, const float* __restrict__ W2,
    const float* __restrict__ b2, float* __restrict__ out, int n)
{
    int i = blockIdx.x * blockDim.x + threadIdx.x;
    if (i >= n) return;

    // ---- load inputs ----
    const float x0 = x[3 * i + 0];
    const float x1 = x[3 * i + 1];
    const float x2 = x[3 * i + 2];

    float z[18];
    z[0] = fast_tanh(x0);
    z[1] = fast_tanh(x1);
    {
        const float4* tp = (const float4*)(t_feat + 16 * (long)i);
        float4 t0 = tp[0], t1 = tp[1], t2 = tp[2], t3 = tp[3];
        z[2]  = t0.x; z[3]  = t0.y; z[4]  = t0.z; z[5]  = t0.w;
        z[6]  = t1.x; z[7]  = t1.y; z[8]  = t1.z; z[9]  = t1.w;
        z[10] = t2.x; z[11] = t2.y; z[12] = t2.z; z[13] = t2.w;
        z[14] = t3.x; z[15] = t3.y; z[16] = t3.z; z[17] = t3.w;
    }

    // ---- layer 1 + relu + layer 2, fused per output column of W1 ----
    // (compiler reorders the fully-unrolled loops: h[j] is computed then
    //  immediately consumed into d[m] -> only z[18]+d[10] live, VGPR~40)
    float h[64];
#pragma unroll
    for (int j = 0; j < 64; ++j) h[j] = b1[j];
#pragma unroll
    for (int k = 0; k < 18; ++k) {
        const float zk = z[k];
#pragma unroll
        for (int j = 0; j < 64; ++j)
            h[j] = fmaf(zk, W1[k * 64 + j], h[j]);
    }

    float d[10];
#pragma unroll
    for (int m = 0; m < 10; ++m) d[m] = b2[m];
#pragma unroll
    for (int j = 0; j < 64; ++j) {
        const float hj = fmaxf(h[j], 0.0f);
#pragma unroll
        for (int m = 0; m < 10; ++m)
            d[m] = fmaf(hj, W2[j * 10 + m], d[m]);
    }
#pragma unroll
    for (int m = 0; m < 10; ++m)
        d[m] = fast_softplus(d[m]) + 0.0001f;

    // ---- knots (_get_xy) ----
    const float dxl2 = d[0], dxl1 = d[1], dxr1 = d[2], dxr2 = d[3];
    const float dyl2 = d[4], dyl1 = d[5], dyr1 = d[6], dyr2 = d[7];
    const float kl = d[8] * 2.0f, kr = d[9] * 2.0f;

    const float xL1 = -dxl1,        yL1 = -dyl1;
    const float xL2 = -dxl1 - dxl2, yL2 = -dyl1 - dyl2;
    const float xR1 = dxr1,         yR1 = dyr1;
    const float xR2 = dxr1 + dxr2,  yR2 = dyr1 + dyr2;
    const float xR3 = xR2 + BIGC,   yR3 = fmaf(kr, BIGC, yR2);
    const float xL3 = xL2 - BIGC,   yL3 = fmaf(-kl, BIGC, yL2);

    // ---- interp: knots strictly increasing (softplus>0), so exactly one
    // segment contains the clamped q. Select it, then ONE rcp-slope. ----
    float q = fminf(fmaxf(x2, xL3 * 0.99f), xR3 * 0.99f);

    float xl = xL3, xr = xL2, yl = yL3, yr = yL2;            // segment 0
    if (q >= xL2) { xl = xL2; xr = xL1; yl = yL2; yr = yL1; } // 1
    if (q >= xL1) { xl = xL1; xr = xR1; yl = yL1; yr = yR1; } // 2
    if (q >= xR1) { xl = xR1; xr = xR2; yl = yR1; yr = yR2; } // 3
    if (q >= xR2) { xl = xR2; xr = xR3; yl = yR2; yr = yR3; } // 4

    const float slope = (yr - yl) * fast_rcp(xr - xl);
    const float res = fmaf(slope, q - xl, yl);

    // ---- output: [x0*mask0, x1*mask1, res] ----
    const float m0 = mask[0];
    const float m1 = mask[1];
    out[3 * i + 0] = x0 * m0;
    out[3 * i + 1] = x1 * m1;
    out[3 * i + 2] = res;
}

extern "C" void kernel_launch(void* const* d_in, const int* in_sizes, int n_in,
                              void* d_out, int out_size, void* d_ws, size_t ws_size,
                              hipStream_t stream) {
    const float* x      = (const float*)d_in[0];
    const float* t_feat = (const float*)d_in[1];
    const float* mask   = (const float*)d_in[2];
    const float* W1     = (const float*)d_in[3];
    const float* b1     = (const float*)d_in[4];
    const float* W2     = (const float*)d_in[5];
    const float* b2     = (const float*)d_in[6];
    float* out = (float*)d_out;

    const int n = in_sizes[0] / 3;  // N points
    const int block = 256;
    const int grid = (n + block - 1) / block;
    coupling_kernel<<<grid, block, 0, stream>>>(x, t_feat, mask, W1, b1, W2, b2, out, n);
}